// Round 2
// baseline (326.751 us; speedup 1.0000x reference)
//
#include <hip/hip_runtime.h>

// image2patch: out[b, i*126+j, r*6+c] = x[b, 0, 2*i + r, 2*j + c]
// IMAGE_SIZE=256, PSIZE=6, STRIDE=2, NPOS=126, BATCH=128, fp32.
//
// R1: coalesced stores + LDS staging (fixed TA/TD-serialized gather).
// R2: issue-path fixes (invariant emit geometry, LDSW=267, XCD swizzle) -> ZERO
//     delta. Dispatch stream shows iteration = [kernel, fill]: kernel is ~118us,
//     i.e. ~2.5 TB/s effective vs the fill's 6.2 TB/s. Not issue-bound.
// R3 (this round): convoy theory. One {6KB read -> barrier -> 18KB write} phase
//     per block means every block-generation opens with an unhidden read-latency
//     bubble while the store pipe idles. Fix: persistent blocks over 9 consecutive
//     i-tiles (126 = 14*9, grid = 1792 = 7 blocks/CU exactly). Consecutive tiles
//     share 4/6 rows: prologue stages 6 rows once; each tile then prefetches only
//     2 new rows (2KB) into REGISTERS during the previous 18KB store burst, and
//     ds-writes them into an 8-row LDS ring (slot = row & 7). Write slots
//     (rows 2i+6,2i+7 over stale 2i-2,2i-1) are disjoint from emit(i)'s read
//     slots (rows 2i..2i+5), so one barrier per tile suffices.

#define IMG 256
#define PSZ 6
#define NPOS 126
#define BATCHN 128
#define LDSW 267                 // 267 % 32 = 11: mixed-parity bank spread, max ~3-way
#define TILES 9                  // consecutive i per block; 126 = 14 * 9
#define NIB (NPOS / TILES)       // 14 i-runs per batch
#define NBLK (BATCHN * NIB)      // 1792 = 7 blocks/CU exactly
#define NXCD 8

__global__ __launch_bounds__(256) void image2patch_kernel(
    const float* __restrict__ x, float* __restrict__ out) {
  __shared__ float ring[8 * LDSW];           // 8.5 KB: 8-row ring, slot = row & 7

  // XCD-chunked bijective swizzle (1792 = 8 * 224): contiguous i-runs / batches
  // stay on one XCD so boundary rows hit that XCD's L2.
  const int cpx = NBLK / NXCD;               // 224
  const int raw = blockIdx.x;
  const int blk = (raw % NXCD) * cpx + raw / NXCD;

  const int b  = blk / NIB;
  const int i0 = (blk - b * NIB) * TILES;
  const int t  = threadIdx.x;

  const float* img = x + (size_t)b * (IMG * IMG);

  // ---- prologue: stage rows 2*i0 .. 2*i0+5 into their ring slots ----
  for (int idx = t; idx < PSZ * (IMG / 4); idx += 256) {   // 384 float4
    const int col4 = idx / PSZ;
    const int rr   = idx - col4 * PSZ;       // row-interleaved: lanes spread rows
    const int R    = 2 * i0 + rr;
    float4 v = reinterpret_cast<const float4*>(img + (size_t)R * IMG)[col4];
    float* d = &ring[(R & 7) * LDSW + col4 * 4];
    d[0] = v.x; d[1] = v.y; d[2] = v.z; d[3] = v.w;        // LDSW odd -> scalar writes
  }

  // ---- per-thread emit geometry (constant across tiles) ----
  // q = t + 252*it => f = 4t + 1008*it; 1008 = 28*36 so j = t/9 + 28*it and
  // k0 = 4*(t mod 9) is per-thread constant; LDS addrs advance by 2*28 = 56.
  const int tj = t / 9;
  const int m  = t - 9 * tj;
  const int k0 = 4 * m;
  const int kA = k0,     rA = kA / PSZ, cA = 2 * tj + (kA - PSZ * rA);
  const int kB = k0 + 1, rB = kB / PSZ, cB = 2 * tj + (kB - PSZ * rB);
  const int kC = k0 + 2, rC = kC / PSZ, cC = 2 * tj + (kC - PSZ * rC);
  const int kD = k0 + 3, rD = kD / PSZ, cD = 2 * tj + (kD - PSZ * rD);

  // prefetch lane geometry: threads 0..127 carry one float4 of rows 2i+6 / 2i+7
  const int pr  = t & 1;                     // row parity
  const int pc4 = t >> 1;                    // float4 column

  __syncthreads();

  for (int tt = 0; tt < TILES; ++tt) {
    const int i   = i0 + tt;
    const int R2i = 2 * i;

    // ---- issue next-tile row loads into regs (hidden under the store burst) ----
    float4 pf;
    const bool do_pf = (t < 128) && (tt < TILES - 1);
    if (do_pf) {
      const int R = R2i + 6 + pr;
      pf = reinterpret_cast<const float4*>(img + (size_t)R * IMG)[pc4];
    }

    // ---- emit tile i: 1134 coalesced float4 stores, gather from ring ----
    if (t < 252) {
      int a0 = ((R2i + rA) & 7) * LDSW + cA;
      int a1 = ((R2i + rB) & 7) * LDSW + cB;
      int a2 = ((R2i + rC) & 7) * LDSW + cC;
      int a3 = ((R2i + rD) & 7) * LDSW + cD;
      float4* outp = reinterpret_cast<float4*>(
          out + ((size_t)b * (NPOS * NPOS) + (size_t)i * NPOS) * (PSZ * PSZ));
      int q = t;
#pragma unroll
      for (int it = 0; it < 4; ++it) {                     // 4*252 = 1008 float4
        float4 v;
        v.x = ring[a0]; v.y = ring[a1]; v.z = ring[a2]; v.w = ring[a3];
        outp[q] = v;
        a0 += 56; a1 += 56; a2 += 56; a3 += 56;
        q += 252;
      }
      if (t < 126) {                                       // tail: q = 1008..1133
        float4 v;
        v.x = ring[a0]; v.y = ring[a1]; v.z = ring[a2]; v.w = ring[a3];
        outp[q] = v;
      }
    }

    // ---- land prefetched rows in the ring (slots of stale rows 2i-2, 2i-1;
    //      disjoint from this tile's read slots, so no barrier needed before) ----
    if (do_pf) {
      const int R = R2i + 6 + pr;
      float* d = &ring[(R & 7) * LDSW + pc4 * 4];
      d[0] = pf.x; d[1] = pf.y; d[2] = pf.z; d[3] = pf.w;
    }
    __syncthreads();   // rows 2i+6, 2i+7 visible to emit(i+1)
  }
}

extern "C" void kernel_launch(void* const* d_in, const int* in_sizes, int n_in,
                              void* d_out, int out_size, void* d_ws, size_t ws_size,
                              hipStream_t stream) {
  const float* x = (const float*)d_in[0];
  float* out = (float*)d_out;
  image2patch_kernel<<<NBLK, 256, 0, stream>>>(x, out);
}

// Round 3
// 317.269 us; speedup vs baseline: 1.0299x; 1.0299x over previous
//
#include <hip/hip_runtime.h>

// image2patch: out[b, i*126+j, r*6+c] = x[b, 0, 2*i + r, 2*j + c]
// IMAGE_SIZE=256, PSIZE=6, STRIDE=2, NPOS=126, BATCH=128, fp32.
//
// R1: coalesced stores + LDS staging.
// R2: issue-path fixes (invariant geometry, LDSW=267, XCD swizzle) -> ZERO delta.
// R3: persistent 9-tile pipeline (read latency hiding) -> ZERO delta (-4%).
//     => kernel is pinned at ~120us (2.4 TB/s) across wildly different schedules
//        while fillBuffer does 6.2 TB/s on the same chip. CU is ~95% issue-idle.
// R4 (this round): attack the store STREAM itself, two mechanisms at once:
//   a) register-gather-then-burst: all 16-20 ds_read_b32 issued independently,
//      ONE lgkmcnt wait, then 4-5 back-to-back stores -- no per-store LDS
//      dependency chain, fill-like burst behavior.
//   b) __builtin_nontemporal_store (nt): don't allocate 293 MB of dirty lines
//      through the 4MB/XCD L2 -- stops input-row eviction (rows re-read 3x)
//      and partial-sector RMW at the 96B-misaligned region edges. fillBuffer's
//      FETCH_SIZE ~= 8KB says it streams; we should too.

#define IMG 256
#define PSZ 6
#define NPOS 126
#define BATCHN 128
#define LDSW 267                 // 267 % 32 = 11: mixed-parity bank spread, max ~3-way
#define NXCD 8

typedef float f32x4 __attribute__((ext_vector_type(4)));

__global__ __launch_bounds__(256) void image2patch_kernel(
    const float* __restrict__ x, float* __restrict__ out) {
  __shared__ float tile[PSZ * LDSW];

  // XCD-chunked bijective swizzle (grid = 16128 = 8 * 2016) — measured neutral,
  // kept for read-side L2 locality.
  const int cpx = (BATCHN * NPOS) / NXCD;          // 2016
  const int raw = blockIdx.x;
  const int blk = (raw % NXCD) * cpx + raw / NXCD; // b*126+i

  const int b = blk / NPOS;
  const int i = blk - b * NPOS;
  const int t = threadIdx.x;

  // ---- stage rows 2i..2i+5 into LDS (coalesced float4, row-interleaved) ----
  const float* src = x + (size_t)b * (IMG * IMG) + (size_t)(2 * i) * IMG;
  for (int idx = t; idx < PSZ * (IMG / 4); idx += 256) {   // 384 float4
    const int col4 = idx / PSZ;
    const int row  = idx - col4 * PSZ;
    float4 v = reinterpret_cast<const float4*>(src + row * IMG)[col4];
    float* d = &tile[row * LDSW + col4 * 4];
    d[0] = v.x; d[1] = v.y; d[2] = v.z; d[3] = v.w;        // LDSW odd -> scalar writes
  }
  __syncthreads();

  // ---- emit: gather ALL of this thread's output into registers, then burst ----
  // q = t + 252*it => f = 4t + 1008*it; 1008 = 28*36 so j = t/9 + 28*it and
  // k0 = 4*(t%9) is per-thread constant; LDS addrs advance by 2*28 = 56 per it.
  if (t < 252) {
    const int tj = t / 9;
    const int m  = t - 9 * tj;
    const int k0 = 4 * m;
    const int kA = k0,     rA = kA / PSZ, cA = 2 * tj + (kA - PSZ * rA);
    const int kB = k0 + 1, rB = kB / PSZ, cB = 2 * tj + (kB - PSZ * rB);
    const int kC = k0 + 2, rC = kC / PSZ, cC = 2 * tj + (kC - PSZ * rC);
    const int kD = k0 + 3, rD = kD / PSZ, cD = 2 * tj + (kD - PSZ * rD);
    const int a0 = rA * LDSW + cA;
    const int a1 = rB * LDSW + cB;
    const int a2 = rC * LDSW + cC;
    const int a3 = rD * LDSW + cD;

    // 16-20 independent ds_read_b32 — compiler batches them, one lgkmcnt wait.
    f32x4 g0, g1, g2, g3, g4;
    g0.x = tile[a0      ]; g0.y = tile[a1      ]; g0.z = tile[a2      ]; g0.w = tile[a3      ];
    g1.x = tile[a0 +  56]; g1.y = tile[a1 +  56]; g1.z = tile[a2 +  56]; g1.w = tile[a3 +  56];
    g2.x = tile[a0 + 112]; g2.y = tile[a1 + 112]; g2.z = tile[a2 + 112]; g2.w = tile[a3 + 112];
    g3.x = tile[a0 + 168]; g3.y = tile[a1 + 168]; g3.z = tile[a2 + 168]; g3.w = tile[a3 + 168];
    if (t < 126) {
      g4.x = tile[a0 + 224]; g4.y = tile[a1 + 224]; g4.z = tile[a2 + 224]; g4.w = tile[a3 + 224];
    }

    // Pure store burst, nontemporal (nt): no L2 dirty-line allocate.
    f32x4* outp = reinterpret_cast<f32x4*>(
        out + ((size_t)b * (NPOS * NPOS) + (size_t)i * NPOS) * (PSZ * PSZ));
    __builtin_nontemporal_store(g0, outp + t);
    __builtin_nontemporal_store(g1, outp + t + 252);
    __builtin_nontemporal_store(g2, outp + t + 504);
    __builtin_nontemporal_store(g3, outp + t + 756);
    if (t < 126) {
      __builtin_nontemporal_store(g4, outp + t + 1008);
    }
  }
}

extern "C" void kernel_launch(void* const* d_in, const int* in_sizes, int n_in,
                              void* d_out, int out_size, void* d_ws, size_t ws_size,
                              hipStream_t stream) {
  const float* x = (const float*)d_in[0];
  float* out = (float*)d_out;
  image2patch_kernel<<<BATCHN * NPOS, 256, 0, stream>>>(x, out);
}